// Round 10
// baseline (906.661 us; speedup 1.0000x reference)
//
#include <hip/hip_runtime.h>
#include <math.h>

#define NSPA 32768           // 32*32*32 spatial positions = L
#define TCH 32               // scan chunk length
#define NCH 1024             // number of chunks = NSPA/TCH
#define EPS 1e-5f

// ---- stats arena offsets (floats, within d_ws[0..65535]) ----
#define ST_MEAN   0      // 192
#define ST_RSTD   192    // 192
#define ST_GM     384    // 192
#define ST_GRSTD  576    // 192
#define ST_X2SUM  768    // 192
#define ST_XH     1024   // 192*32
#define ST_XW     7168   // 192*32
#define ST_XD     13312  // 192*32
#define ST_GATE   19456  // 16*12*96 = 18432
#define ST_MEAN2  38400  // 192
#define ST_RSTD2  38592  // 192
#define ST_WT     40960  // 3888: conv3 weights transposed [ci][tap][co]

__device__ __forceinline__ float sigmoidf_(float x){ return 1.f/(1.f+__expf(-x)); }
__device__ __forceinline__ float siluf_(float x){ return x/(1.f+__expf(-x)); }
__device__ __forceinline__ float geluf_(float x){ return 0.5f*x*(1.f+erff(x*0.70710678118654752f)); }
__device__ __forceinline__ float softplusf_(float x){ return fmaxf(x,0.f) + log1pf(__expf(-fabsf(x))); }

// ============ K0: all weight transposes in one kernel ============
// idx ranges: wt 3888 | W1t 36864 | W2t 36864 | Wipt 36864 | xpWt 9216 | Wot 18432
__global__ void k_prep(const float* __restrict__ c3w, const float* __restrict__ W1,
                       const float* __restrict__ W2, const float* __restrict__ Wip,
                       const float* __restrict__ xpw, const float* __restrict__ Wout,
                       float* __restrict__ wt, float* __restrict__ W1t,
                       float* __restrict__ W2t, float* __restrict__ Wipt,
                       float* __restrict__ xpWt, float* __restrict__ Wot) {
  int idx = blockIdx.x*256 + threadIdx.x;
  if (idx < 3888) {
    int co = idx/324, r = idx%324;
    wt[r*12+co] = c3w[co*324+r];
  } else if (idx < 40752) {
    int i = idx-3888; int k = i/384, h = i%384;
    W1t[i] = W1[(size_t)h*96+k];
  } else if (idx < 77616) {
    int i = idx-40752; int k = i/96, o = i%96;
    W2t[i] = W2[(size_t)o*384+k];
  } else if (idx < 114480) {
    int i = idx-77616; int k = i/384, r = i%384;
    Wipt[i] = Wip[(size_t)r*96+k];
  } else if (idx < 123696) {
    int i = idx-114480; int e = i/48, o = i%48;
    float v = 0.f;
    if (o < 38) { int row = (o<32)? (o+6) : (o-32); v = xpw[(size_t)row*192+e]; }
    xpWt[i] = v;
  } else if (idx < 142128) {
    int i = idx-123696; int e = i/96, o = i%96;
    Wot[i] = Wout[(size_t)o*192+e];
  }
}

// ============ K1: per-(b,c) instance-norm stats + SPPE pooled means ============
// grid 192, block 1024
__global__ void k_stats(const float* __restrict__ x, float* __restrict__ st) {
  int bc = blockIdx.x;
  int t = threadIdx.x;
  __shared__ float xh_s[32], xw_s[32], xd_s[32], red[16], red2[16];
  if (t < 32) { xh_s[t]=0.f; xw_s[t]=0.f; xd_s[t]=0.f; }
  __syncthreads();
  const float* px = x + (size_t)bc*NSPA;
  float s=0.f, s2=0.f;
  for (int it=0; it<32; ++it) {
    float v = px[it*1024 + t];
    s += v; s2 += v*v;
    float wv = v;
    #pragma unroll
    for (int m=32;m>=1;m>>=1) wv += __shfl_xor(wv,m);
    if ((t&63)==0) atomicAdd(&xh_s[it], wv);
  }
  atomicAdd(&xw_s[(t>>5)&31], s);
  atomicAdd(&xd_s[t&31], s);
  float rs=s, rs2=s2;
  #pragma unroll
  for (int m=32;m>=1;m>>=1){ rs += __shfl_xor(rs,m); rs2 += __shfl_xor(rs2,m); }
  if ((t&63)==0){ red[t>>6]=rs; red2[t>>6]=rs2; }
  __syncthreads();
  if (t==0){
    float S=0.f,S2=0.f;
    for (int w=0;w<16;w++){ S+=red[w]; S2+=red2[w]; }
    float mn = S/(float)NSPA;
    float var = S2/(float)NSPA - mn*mn;
    st[ST_MEAN+bc] = mn;
    st[ST_RSTD+bc] = rsqrtf(var+EPS);
  }
  if (t<32){
    st[ST_XH + bc*32 + t] = xh_s[t]*(1.f/1024.f);
    st[ST_XW + bc*32 + t] = xw_s[t]*(1.f/1024.f);
    st[ST_XD + bc*32 + t] = xd_s[t]*(1.f/1024.f);
  }
}

// ============ K2: SPPE 1x1 conv on pooled vectors -> sigmoid gates ============
__global__ void k_gates(const float* __restrict__ c1w, const float* __restrict__ c1b,
                        float* __restrict__ st) {
  int bg = blockIdx.x; int b = bg>>3; int g = bg&7;
  for (int i = threadIdx.x; i < 12*96; i += 128) {
    int co = i/96, pos = i%96;
    float acc = c1b[co];
    for (int cg=0; cg<12; ++cg) {
      int bc = b*96 + g*12 + cg;
      float hv;
      if (pos < 32)      hv = st[ST_XH + bc*32 + pos];
      else if (pos < 64) hv = st[ST_XW + bc*32 + pos-32];
      else               hv = st[ST_XD + bc*32 + pos-64];
      acc += c1w[co*12+cg]*hv;
    }
    st[ST_GATE + bg*1152 + i] = sigmoidf_(acc);
  }
}

// ============ K3: gated = gx*gh*gw*gd, + group-norm stats ============
__global__ void k_gated(const float* __restrict__ x, float* __restrict__ gated,
                        float* __restrict__ st) {
  int bc = blockIdx.x; int bg = bc/12; int cg = bc%12;
  int t = threadIdx.x;
  const float* gate = st + ST_GATE + bg*1152 + cg*96;
  float gw = gate[32 + (t>>5)];
  float gd = gate[64 + (t&31)];
  const float* px = x + (size_t)bc*NSPA;
  float* pg = gated + (size_t)bc*NSPA;
  __shared__ float red[16], red2[16];
  float s=0.f, s2=0.f;
  for (int it=0; it<32; ++it) {
    float gh = gate[it];
    float v = px[it*1024+t]*gh*gw*gd;
    pg[it*1024+t] = v;
    s += v; s2 += v*v;
  }
  #pragma unroll
  for (int m=32;m>=1;m>>=1){ s += __shfl_xor(s,m); s2 += __shfl_xor(s2,m); }
  if ((t&63)==0){ red[t>>6]=s; red2[t>>6]=s2; }
  __syncthreads();
  if (t==0){
    float S=0.f,S2=0.f;
    for (int w=0;w<16;w++){ S+=red[w]; S2+=red2[w]; }
    float mn = S/(float)NSPA;
    float var = S2/(float)NSPA - mn*mn;
    st[ST_GM+bc] = mn;
    st[ST_GRSTD+bc] = rsqrtf(var+EPS);
  }
}

// ============ K4: grouped 3x3x3 conv via LDS ring-slabs + per-channel sums ============
// grid (4, 8, 16) = (2x2 wd-tiles, 8 h-chunks of 4, bg); block 256 (16w x 16d).
__global__ void k_conv3(const float* __restrict__ x, const float* __restrict__ wt,
                        const float* __restrict__ c3b, float* __restrict__ x2,
                        float* __restrict__ st) {
  __shared__ float sl[3][12*324];
  __shared__ float ssum[12];
  int bg = blockIdx.z;
  int w0 = (blockIdx.x & 1)*16, d0 = (blockIdx.x >> 1)*16;
  int h0 = blockIdx.y*4;
  int tid = threadIdx.x;
  if (tid < 12) ssum[tid] = 0.f;

  const float* xb = x + (size_t)bg*12*NSPA;

  auto load_slab = [&](int hh, int s){
    for (int i=tid; i<3888; i+=256){
      int ci = i/324, r = i%324;
      int lw = r/18, ld = r%18;
      int gw = w0-1+lw, gd = d0-1+ld;
      float v = 0.f;
      if ((unsigned)hh<32u && (unsigned)gw<32u && (unsigned)gd<32u)
        v = xb[(size_t)ci*NSPA + hh*1024 + gw*32 + gd];
      sl[s][i] = v;
    }
  };

  load_slab(h0-1, ((h0-1)%3+3)%3);
  load_slab(h0,   h0%3);
  load_slab(h0+1, (h0+1)%3);
  __syncthreads();

  int w = tid>>4, d = tid&15;
  int base_wd = w*18 + d;
  float b0v=c3b[0],b1v=c3b[1],b2v=c3b[2],b3v=c3b[3],b4v=c3b[4],b5v=c3b[5],
        b6v=c3b[6],b7v=c3b[7],b8v=c3b[8],b9v=c3b[9],b10v=c3b[10],b11v=c3b[11];

  for (int it=0; it<4; ++it){
    int h = h0 + it;
    const float* sm1 = sl[((h-1)%3+3)%3];
    const float* s00 = sl[h%3];
    const float* sp1 = sl[(h+1)%3];
    float acc[12];
    acc[0]=b0v; acc[1]=b1v; acc[2]=b2v; acc[3]=b3v; acc[4]=b4v; acc[5]=b5v;
    acc[6]=b6v; acc[7]=b7v; acc[8]=b8v; acc[9]=b9v; acc[10]=b10v; acc[11]=b11v;
    for (int ci=0; ci<12; ++ci){
      const float* w_ci = wt + ci*324;
      #pragma unroll
      for (int kh=0;kh<3;kh++){
        const float* sp = (kh==0)? sm1 : ((kh==1)? s00 : sp1);
        const float* srow = sp + ci*324 + base_wd;
        #pragma unroll
        for (int kw=0;kw<3;kw++){
          #pragma unroll
          for (int kd=0;kd<3;kd++){
            float v = srow[kw*18 + kd];
            const float4* wp = (const float4*)(w_ci + (kh*9+kw*3+kd)*12);
            float4 wa = wp[0], wb = wp[1], wc = wp[2];
            acc[0]=fmaf(wa.x,v,acc[0]); acc[1]=fmaf(wa.y,v,acc[1]);
            acc[2]=fmaf(wa.z,v,acc[2]); acc[3]=fmaf(wa.w,v,acc[3]);
            acc[4]=fmaf(wb.x,v,acc[4]); acc[5]=fmaf(wb.y,v,acc[5]);
            acc[6]=fmaf(wb.z,v,acc[6]); acc[7]=fmaf(wb.w,v,acc[7]);
            acc[8]=fmaf(wc.x,v,acc[8]); acc[9]=fmaf(wc.y,v,acc[9]);
            acc[10]=fmaf(wc.z,v,acc[10]); acc[11]=fmaf(wc.w,v,acc[11]);
          }
        }
      }
    }
    int l = h*1024 + (w0+w)*32 + (d0+d);
    #pragma unroll
    for (int co=0;co<12;co++){
      float r = acc[co];
      x2[(size_t)(bg*12+co)*NSPA + l] = r;
      float rv = r;
      #pragma unroll
      for (int m=32;m>=1;m>>=1) rv += __shfl_xor(rv,m);
      if ((tid&63)==0) atomicAdd(&ssum[co], rv);
    }
    __syncthreads();
    if (it<3){
      load_slab(h+2, (h+2)%3);
      __syncthreads();
    }
  }
  if (tid<12) atomicAdd(&st[ST_X2SUM + bg*12 + tid], ssum[tid]);
}

// ============ K5: SPPE attention weights -> per-(bg,l) sigmoid gate only ============
__global__ void k_sppe_out(const float* __restrict__ gated,
                           const float* __restrict__ x2, const float* __restrict__ gnw,
                           const float* __restrict__ gnb, const float* __restrict__ st,
                           float* __restrict__ sigb) {
  int bg = blockIdx.y; int b = bg>>3; int g = bg&7;
  __shared__ float x11s[12], alphas[12], betasum_s;
  if (threadIdx.x==0){
    float m1=-1e30f, m2=-1e30f;
    float mu2[12];
    for (int cg=0;cg<12;cg++){
      int bc=b*96+g*12+cg;
      mu2[cg] = st[ST_X2SUM+bc]*(1.f/(float)NSPA);
      m1 = fmaxf(m1, gnb[cg]); m2 = fmaxf(m2, mu2[cg]);
    }
    float e1[12], e2[12]; float s1=0.f, s2=0.f;
    for (int cg=0;cg<12;cg++){ e1[cg]=expf(gnb[cg]-m1); s1+=e1[cg];
                               e2[cg]=expf(mu2[cg]-m2); s2+=e2[cg]; }
    float bs=0.f;
    for (int cg=0;cg<12;cg++){
      int bc=b*96+g*12+cg;
      float x11 = e1[cg]/s1;
      float x21 = e2[cg]/s2;
      x11s[cg]=x11;
      float gr = st[ST_GRSTD+bc], gm = st[ST_GM+bc];
      alphas[cg] = x21*gr*gnw[cg];
      bs += x21*(gnb[cg] - gm*gr*gnw[cg]);
    }
    betasum_s = bs;
  }
  __syncthreads();
  int l = blockIdx.x*256 + threadIdx.x;
  float wsum = betasum_s;
  int bc0 = b*96+g*12;
  for (int cg=0;cg<12;cg++){
    size_t off = (size_t)(bc0+cg)*NSPA + l;
    wsum += x11s[cg]*x2[off] + alphas[cg]*gated[off];
  }
  sigb[(size_t)bg*NSPA + l] = sigmoidf_(wsum);
}

// ============ K6: FUSED in_proj (inorm folded) + causal conv1d + silu ============
// Halo xm (tokens l0-3..l0-1) computed from LDS-staged normalized columns against
// Wipt (k-major, coalesced). grid (512,2), block 256.
__global__ void k_front(const float* __restrict__ x, const float* __restrict__ Wipt,
                        const float* __restrict__ cw, const float* __restrict__ cb,
                        const float* __restrict__ st,
                        float* __restrict__ xc_t, float* __restrict__ zg_t) {
  __shared__ float As[96*64];     // normalized x tile [k][l]
  __shared__ float outS[48*65];   // per-phase output staging [row][l] (padded)
  __shared__ float haloS[3*192];  // xm at tokens l0-3..l0-1
  __shared__ float xhS[3*96];     // normalized x at halo tokens [j][k]
  int b = blockIdx.y; int l0 = blockIdx.x*64; int tid = threadIdx.x;
  const float* mean = st + ST_MEAN + b*96;
  const float* rstd = st + ST_RSTD + b*96;
  for (int i=tid;i<96*64;i+=256){
    int k=i>>6, l=i&63;
    As[i] = (x[((size_t)b*96+k)*NSPA + l0+l]-mean[k])*rstd[k];
  }
  for (int i=tid;i<288;i+=256){
    int j=i/96, k=i%96;
    int t = l0-3+j;
    xhS[i] = (t>=0) ? (x[((size_t)b*96+k)*NSPA + t]-mean[k])*rstd[k] : 0.f;
  }
  __syncthreads();
  for (int i=tid;i<576;i+=256){
    int j=i/192, e=i%192;
    const float* xh = xhS + j*96;
    float s = 0.f;
    for (int k=0;k<96;k++) s = fmaf(Wipt[(size_t)k*384 + e], xh[k], s);
    haloS[j*192+e] = s;
  }
  __syncthreads();
  int wv = __builtin_amdgcn_readfirstlane(tid>>6);
  int lane = tid&63;
  for (int p=0;p<8;++p){
    int r0 = p*48 + wv*12;
    float acc[12];
    #pragma unroll
    for (int j=0;j<12;j++) acc[j]=0.f;
    for (int k=0;k<96;k++){
      float a = As[k*64+lane];
      const float4* wp = (const float4*)&Wipt[(size_t)k*384 + r0];
      float4 w0=wp[0],w1=wp[1],w2=wp[2];
      acc[0]=fmaf(w0.x,a,acc[0]);  acc[1]=fmaf(w0.y,a,acc[1]);
      acc[2]=fmaf(w0.z,a,acc[2]);  acc[3]=fmaf(w0.w,a,acc[3]);
      acc[4]=fmaf(w1.x,a,acc[4]);  acc[5]=fmaf(w1.y,a,acc[5]);
      acc[6]=fmaf(w1.z,a,acc[6]);  acc[7]=fmaf(w1.w,a,acc[7]);
      acc[8]=fmaf(w2.x,a,acc[8]);  acc[9]=fmaf(w2.y,a,acc[9]);
      acc[10]=fmaf(w2.z,a,acc[10]); acc[11]=fmaf(w2.w,a,acc[11]);
    }
    if (p) __syncthreads();
    if (p < 4){
      #pragma unroll
      for (int j=0;j<12;j++){
        int e = r0 + j;
        float v = acc[j];
        float vm1 = __shfl_up(v,1);
        float vm2 = __shfl_up(v,2);
        float vm3 = __shfl_up(v,3);
        if (lane==0) vm1 = haloS[2*192+e];
        if (lane<=1) vm2 = haloS[(1+lane)*192+e];
        if (lane<=2) vm3 = haloS[(0+lane)*192+e];
        float4 w4 = *(const float4*)&cw[e*4];
        float r_ = cb[e] + w4.x*vm3 + w4.y*vm2 + w4.z*vm1 + w4.w*v;
        outS[(wv*12+j)*65 + lane] = siluf_(r_);
      }
    } else {
      #pragma unroll
      for (int j=0;j<12;j++) outS[(wv*12+j)*65 + lane] = acc[j];
    }
    __syncthreads();
    float* dst = (p<4) ? xc_t : zg_t;
    int e0 = (p<4) ? p*48 : (p-4)*48;
    for (int i=tid; i<64*12; i+=256){
      int l = i/12, q = i%12;
      float4 v;
      v.x = outS[(q*4+0)*65 + l];
      v.y = outS[(q*4+1)*65 + l];
      v.z = outS[(q*4+2)*65 + l];
      v.w = outS[(q*4+3)*65 + l];
      *(float4*)&dst[((size_t)b*NSPA + l0+l)*192 + e0 + q*4] = v;
    }
  }
}

// ============ K7: x_proj GEMM, uniform s_load weights, staged flush ============
__global__ void k_gemm_xp(const float* __restrict__ A, const float* __restrict__ xpWt,
                          float* __restrict__ dbl_t) {
  __shared__ float As[96*65];
  __shared__ float dblS[48*65];
  int b = blockIdx.y; int l0 = blockIdx.x*64; int tid = threadIdx.x;
  int wv = __builtin_amdgcn_readfirstlane(tid>>6);
  int lane = tid&63;
  int o0 = wv*12;
  float acc[12];
  #pragma unroll
  for (int j=0;j<12;j++) acc[j]=0.f;
  for (int h=0;h<2;++h){
    if (h) __syncthreads();
    for (int i=tid;i<64*24;i+=256){
      int l=i/24, q=i%24;
      float4 v = *(const float4*)&A[((size_t)b*NSPA + l0+l)*192 + h*96 + q*4];
      As[(q*4+0)*65+l]=v.x; As[(q*4+1)*65+l]=v.y;
      As[(q*4+2)*65+l]=v.z; As[(q*4+3)*65+l]=v.w;
    }
    __syncthreads();
    for (int k=0;k<96;k++){
      float a = As[k*65+lane];
      const float4* wp = (const float4*)&xpWt[(size_t)(h*96+k)*48 + o0];
      float4 w0=wp[0],w1=wp[1],w2=wp[2];
      acc[0]=fmaf(w0.x,a,acc[0]);  acc[1]=fmaf(w0.y,a,acc[1]);
      acc[2]=fmaf(w0.z,a,acc[2]);  acc[3]=fmaf(w0.w,a,acc[3]);
      acc[4]=fmaf(w1.x,a,acc[4]);  acc[5]=fmaf(w1.y,a,acc[5]);
      acc[6]=fmaf(w1.z,a,acc[6]);  acc[7]=fmaf(w1.w,a,acc[7]);
      acc[8]=fmaf(w2.x,a,acc[8]);  acc[9]=fmaf(w2.y,a,acc[9]);
      acc[10]=fmaf(w2.z,a,acc[10]); acc[11]=fmaf(w2.w,a,acc[11]);
    }
  }
  __syncthreads();
  #pragma unroll
  for (int j=0;j<12;j++) dblS[(o0+j)*65 + lane] = acc[j];
  __syncthreads();
  for (int i=tid;i<64*10;i+=256){
    int l=i/10, q=i%10;
    float4 v;
    v.x = dblS[(q*4+0)*65+l]; v.y = dblS[(q*4+1)*65+l];
    v.z = dblS[(q*4+2)*65+l]; v.w = dblS[(q*4+3)*65+l];
    *(float4*)&dbl_t[((size_t)b*NSPA + l0+l)*40 + q*4] = v;
  }
}

// ============ scan phase A: lane = e, 16 states in registers ============
// x column preloaded into 32 regs (all loads in flight at once), compute loop
// fully unrolled. Power-tree dA (1 exp vs 16, guarded). grid (NCH,2), 192.
__global__ void __launch_bounds__(192, 4)
k_scanA(const float* __restrict__ xc_t, const float* __restrict__ dbl_t,
        const float* __restrict__ dtw, const float* __restrict__ dtb,
        const float* __restrict__ A_log,
        float* __restrict__ P, float* __restrict__ hend) {
  int b = blockIdx.y, ch = blockIdx.x; int e = threadIdx.x;
  float An[16];
  #pragma unroll
  for (int n=0;n<16;n++) An[n] = -__expf(A_log[e*16+n]);
  float An0 = An[0];
  bool fast = true;
  #pragma unroll
  for (int n=0;n<16;n++)
    fast = fast && (fabsf(An[n] - (float)(n+1)*An0) <= 1e-4f*(float)(n+1));
  float wdt[6];
  #pragma unroll
  for (int j=0;j<6;j++) wdt[j]=dtw[e*6+j];
  float bdt = dtb[e];
  const float* drow = dbl_t + ((size_t)b*NSPA + (size_t)ch*TCH)*40;
  const float* xrow = xc_t + ((size_t)b*NSPA + (size_t)ch*TCH)*192 + e;
  float h[16], Pp[16];
  #pragma unroll
  for (int n=0;n<16;n++){ h[n]=0.f; Pp[n]=1.f; }
  if (fast){
    float xv[TCH];
    #pragma unroll
    for (int l=0;l<TCH;l++) xv[l] = xrow[(size_t)l*192];
    #pragma unroll
    for (int l=0;l<TCH;l++){
      const float* u = drow + l*40;
      float4 b0=*(const float4*)(u+0), b1=*(const float4*)(u+4),
             b2=*(const float4*)(u+8), b3=*(const float4*)(u+12);
      float4 d4=*(const float4*)(u+32);
      float2 d2=*(const float2*)(u+36);
      float pre = bdt + wdt[0]*d4.x + wdt[1]*d4.y + wdt[2]*d4.z
                      + wdt[3]*d4.w + wdt[4]*d2.x + wdt[5]*d2.y;
      float dte = softplusf_(pre);
      float dtx = dte*xv[l];
      float Bv[16] = {b0.x,b0.y,b0.z,b0.w, b1.x,b1.y,b1.z,b1.w,
                      b2.x,b2.y,b2.z,b2.w, b3.x,b3.y,b3.z,b3.w};
      float r1 = __expf(dte*An0);
      float r2=r1*r1, r3=r2*r1, r4=r2*r2;
      float r5=r4*r1, r6=r4*r2, r7=r4*r3, r8=r4*r4;
      float av[16] = {r1,r2,r3,r4,r5,r6,r7,r8,
                      r8*r1,r8*r2,r8*r3,r8*r4,r8*r5,r8*r6,r8*r7,r8*r8};
      #pragma unroll
      for (int n=0;n<16;n++){
        Pp[n] *= av[n];
        h[n] = h[n]*av[n] + dtx*Bv[n];
      }
    }
  } else {
    for (int l=0;l<TCH;l++){
      const float* u = drow + l*40;
      float4 b0=*(const float4*)(u+0), b1=*(const float4*)(u+4),
             b2=*(const float4*)(u+8), b3=*(const float4*)(u+12);
      float4 d4=*(const float4*)(u+32);
      float2 d2=*(const float2*)(u+36);
      float x = xrow[(size_t)l*192];
      float pre = bdt + wdt[0]*d4.x + wdt[1]*d4.y + wdt[2]*d4.z
                      + wdt[3]*d4.w + wdt[4]*d2.x + wdt[5]*d2.y;
      float dte = softplusf_(pre);
      float dtx = dte*x;
      float Bv[16] = {b0.x,b0.y,b0.z,b0.w, b1.x,b1.y,b1.z,b1.w,
                      b2.x,b2.y,b2.z,b2.w, b3.x,b3.y,b3.z,b3.w};
      #pragma unroll
      for (int n=0;n<16;n++){
        float a = __expf(dte*An[n]);
        Pp[n] *= a;
        h[n] = h[n]*a + dtx*Bv[n];
      }
    }
  }
  size_t o = (((size_t)b*NCH+ch)*192+e)*16;
  #pragma unroll
  for (int q=0;q<4;q++){
    float4 rp; rp.x=Pp[q*4+0]; rp.y=Pp[q*4+1]; rp.z=Pp[q*4+2]; rp.w=Pp[q*4+3];
    *(float4*)&P[o+q*4] = rp;
    float4 rh; rh.x=h[q*4+0]; rh.y=h[q*4+1]; rh.z=h[q*4+2]; rh.w=h[q*4+3];
    *(float4*)&hend[o+q*4] = rh;
  }
}

// ============ scan phase B: PARALLEL segmented inter-chunk combine ============
__global__ void k_scanB(const float* __restrict__ P, const float* __restrict__ hend,
                        float* __restrict__ Hs) {
  __shared__ float sP[16][64], sH[16][64];
  int b = blockIdx.y;
  int rl = threadIdx.x & 63;
  int cg = threadIdx.x >> 6;               // 0..15
  int r  = blockIdx.x*64 + rl;             // 0..3071 within batch
  size_t base = (size_t)b*NCH*3072 + r;
  int c0 = cg*64;
  float Pl = 1.f, hl = 0.f;
  for (int c=c0; c<c0+64; ++c){
    size_t idx = base + (size_t)c*3072;
    float Pc = P[idx], Hc = hend[idx];
    hl = fmaf(Pc, hl, Hc);
    Pl *= Pc;
  }
  sP[cg][rl] = Pl; sH[cg][rl] = hl;
  __syncthreads();
  float H = 0.f;
  for (int g=0; g<cg; ++g) H = fmaf(sP[g][rl], H, sH[g][rl]);
  for (int c=c0; c<c0+64; ++c){
    size_t idx = base + (size_t)c*3072;
    float Pc = P[idx], Hc = hend[idx];
    Hs[idx] = H;
    H = fmaf(Pc, H, Hc);
  }
}

// ============ scan phase C: seeded re-scan + y epilogue + FUSED out_proj ==========
// x/z columns preloaded into 64 regs (all loads in flight), compute unrolled.
// Power-tree dA. y kept in LDS; out_proj in-block. grid (NCH, 2), block 192.
__global__ void __launch_bounds__(192, 4)
k_scanC(const float* __restrict__ xc_t, const float* __restrict__ dbl_t,
        const float* __restrict__ dtw, const float* __restrict__ dtb,
        const float* __restrict__ A_log, const float* __restrict__ Hs,
        const float* __restrict__ ssm_D, const float* __restrict__ zg_t,
        const float* __restrict__ Wot, float* __restrict__ out) {
  __shared__ float yS[32*193];   // [l][e], pad 193 -> conflict-free both phases
  int b = blockIdx.y, ch = blockIdx.x; int e = threadIdx.x;
  float An[16];
  #pragma unroll
  for (int n=0;n<16;n++) An[n] = -__expf(A_log[e*16+n]);
  float An0 = An[0];
  bool fast = true;
  #pragma unroll
  for (int n=0;n<16;n++)
    fast = fast && (fabsf(An[n] - (float)(n+1)*An0) <= 1e-4f*(float)(n+1));
  float wdt[6];
  #pragma unroll
  for (int j=0;j<6;j++) wdt[j]=dtw[e*6+j];
  float bdt = dtb[e];
  float Dv = ssm_D[e];
  const float* drow = dbl_t + ((size_t)b*NSPA + (size_t)ch*TCH)*40;
  const float* xrow = xc_t + ((size_t)b*NSPA + (size_t)ch*TCH)*192 + e;
  const float* zrow = zg_t + ((size_t)b*NSPA + (size_t)ch*TCH)*192 + e;
  float h[16];
  size_t ho = (((size_t)b*NCH+ch)*192+e)*16;
  #pragma unroll
  for (int q=0;q<4;q++){
    float4 hv = *(const float4*)&Hs[ho+q*4];
    h[q*4+0]=hv.x; h[q*4+1]=hv.y; h[q*4+2]=hv.z; h[q*4+3]=hv.w;
  }
  if (fast){
    float xv[TCH], zv[TCH];
    #pragma unroll
    for (int l=0;l<TCH;l++) xv[l] = xrow[(size_t)l*192];
    #pragma unroll
    for (int l=0;l<TCH;l++) zv[l] = zrow[(size_t)l*192];
    #pragma unroll
    for (int l=0;l<TCH;l++){
      const float* u = drow + l*40;
      float4 b0=*(const float4*)(u+0), b1=*(const float4*)(u+4),
             b2=*(const float4*)(u+8), b3=*(const float4*)(u+12);
      float4 c0=*(const float4*)(u+16), c1=*(const float4*)(u+20),
             c2=*(const float4*)(u+24), c3=*(const float4*)(u+28);
      float4 d4=*(const float4*)(u+32);
      float2 d2=*(const float2*)(u+36);
      float pre = bdt + wdt[0]*d4.x + wdt[1]*d4.y + wdt[2]*d4.z
                      + wdt[3]*d4.w + wdt[4]*d2.x + wdt[5]*d2.y;
      float dte = softplusf_(pre);
      float dtx = dte*xv[l];
      float Bv[16] = {b0.x,b0.y,b0.z,b0.w, b1.x,b1.y,b1.z,b1.w,
                      b2.x,b2.y,b2.z,b2.w, b3.x,b3.y,b3.z,b3.w};
      float Cv[16] = {c0.x,c0.y,c0.z,c0.w, c1.x,c1.y,c1.z,c1.w,
                      c2.x,c2.y,c2.z,c2.w, c3.x,c3.y,c3.z,c3.w};
      float r1 = __expf(dte*An0);
      float r2=r1*r1, r3=r2*r1, r4=r2*r2;
      float r5=r4*r1, r6=r4*r2, r7=r4*r3, r8=r4*r4;
      float av[16] = {r1,r2,r3,r4,r5,r6,r7,r8,
                      r8*r1,r8*r2,r8*r3,r8*r4,r8*r5,r8*r6,r8*r7,r8*r8};
      float yp = 0.f;
      #pragma unroll
      for (int n=0;n<16;n++){
        h[n] = h[n]*av[n] + dtx*Bv[n];
        yp += h[n]*Cv[n];
      }
      yS[l*193 + e] = (yp + xv[l]*Dv)*siluf_(zv[l]);
    }
  } else {
    for (int l=0;l<TCH;l++){
      const float* u = drow + l*40;
      float4 b0=*(const float4*)(u+0), b1=*(const float4*)(u+4),
             b2=*(const float4*)(u+8), b3=*(const float4*)(u+12);
      float4 c0=*(const float4*)(u+16), c1=*(const float4*)(u+20),
             c2=*(const float4*)(u+24), c3=*(const float4*)(u+28);
      float4 d4=*(const float4*)(u+32);
      float2 d2=*(const float2*)(u+36);
      float x = xrow[(size_t)l*192];
      float z = zrow[(size_t)l*192];
      float pre = bdt + wdt[0]*d4.x + wdt[1]*d4.y + wdt[2]*d4.z
                      + wdt[3]*d4.w + wdt[4]*d2.x + wdt[5]*d2.y;
      float dte = softplusf_(pre);
      float dtx = dte*x;
      float Bv[16] = {b0.x,b0.y,b0.z,b0.w, b1.x,b1.y,b1.z,b1.w,
                      b2.x,b2.y,b2.z,b2.w, b3.x,b3.y,b3.z,b3.w};
      float Cv[16] = {c0.x,c0.y,c0.z,c0.w, c1.x,c1.y,c1.z,c1.w,
                      c2.x,c2.y,c2.z,c2.w, c3.x,c3.y,c3.z,c3.w};
      float yp = 0.f;
      #pragma unroll
      for (int n=0;n<16;n++){
        float a = __expf(dte*An[n]);
        h[n] = h[n]*a + dtx*Bv[n];
        yp += h[n]*Cv[n];
      }
      yS[l*193 + e] = (yp + x*Dv)*siluf_(z);
    }
  }
  __syncthreads();
  // ---- out_proj: thread (l = tid&31, og = tid>>5) computes 16 outputs ----
  int tl = e & 31;          // token within chunk
  int og = e >> 5;          // 0..5
  int o0 = og*16;
  float acc[16];
  #pragma unroll
  for (int i=0;i<16;i++) acc[i]=0.f;
  const float* yrowS = yS + tl*193;
  for (int k=0;k<192;k++){
    float a = yrowS[k];
    const float4* wp = (const float4*)&Wot[(size_t)k*96 + o0];
    float4 w0=wp[0], w1=wp[1], w2=wp[2], w3=wp[3];
    acc[0]=fmaf(w0.x,a,acc[0]);  acc[1]=fmaf(w0.y,a,acc[1]);
    acc[2]=fmaf(w0.z,a,acc[2]);  acc[3]=fmaf(w0.w,a,acc[3]);
    acc[4]=fmaf(w1.x,a,acc[4]);  acc[5]=fmaf(w1.y,a,acc[5]);
    acc[6]=fmaf(w1.z,a,acc[6]);  acc[7]=fmaf(w1.w,a,acc[7]);
    acc[8]=fmaf(w2.x,a,acc[8]);  acc[9]=fmaf(w2.y,a,acc[9]);
    acc[10]=fmaf(w2.z,a,acc[10]); acc[11]=fmaf(w2.w,a,acc[11]);
    acc[12]=fmaf(w3.x,a,acc[12]); acc[13]=fmaf(w3.y,a,acc[13]);
    acc[14]=fmaf(w3.z,a,acc[14]); acc[15]=fmaf(w3.w,a,acc[15]);
  }
  int lbase = ch*TCH + tl;
  #pragma unroll
  for (int j=0;j<16;j++){
    out[((size_t)b*96 + o0+j)*NSPA + lbase] = acc[j];
  }
}

// ============ K15: instance-norm stats of `out` (round-1 proven) ============
__global__ void k_stats2(const float* __restrict__ outb, float* __restrict__ st) {
  int bc = blockIdx.x; int t = threadIdx.x;
  const float* p = outb + (size_t)bc*NSPA;
  float s=0.f, s2=0.f;
  for (int i=t;i<NSPA;i+=256){ float v=p[i]; s+=v; s2+=v*v; }
  __shared__ float red[4], red2[4];
  #pragma unroll
  for (int m=32;m>=1;m>>=1){ s += __shfl_xor(s,m); s2 += __shfl_xor(s2,m); }
  if ((t&63)==0){ red[t>>6]=s; red2[t>>6]=s2; }
  __syncthreads();
  if (t==0){
    float S=red[0]+red[1]+red[2]+red[3];
    float S2=red2[0]+red2[1]+red2[2]+red2[3];
    float mn=S/(float)NSPA; float var=S2/(float)NSPA-mn*mn;
    st[ST_MEAN2+bc]=mn; st[ST_RSTD2+bc]=rsqrtf(var+EPS);
  }
}

// ============ K16: FUSED MLP (round-5 proven: 256 thr, 6 chunks of 64) ==========
// lane = token; wv = wave (4). Per hidden chunk of 64: fc1 16 rows/wave -> gelu ->
// hidS, fc2 partial for o0=wv*24..+23. LDS: 24KB + 16KB = 40KB. grid (512,2).
__global__ void k_mlpF(const float* __restrict__ outb, const float* __restrict__ sigb,
                       const float* __restrict__ st,
                       const float* __restrict__ W1t, const float* __restrict__ b1,
                       const float* __restrict__ W2t, const float* __restrict__ b2,
                       const float* __restrict__ x, float* __restrict__ dout) {
  __shared__ float xoS[96*64];
  __shared__ float hidS[64*64];
  int b = blockIdx.y; int l0 = blockIdx.x*64; int tid = threadIdx.x;
  for (int i=tid;i<96*64;i+=256){
    int k=i>>6, l=i&63;
    size_t off = ((size_t)b*96+k)*NSPA + l0+l;
    float sv = sigb[((size_t)(b*8 + k/12))*NSPA + l0+l];
    xoS[i] = (outb[off]-st[ST_MEAN2+b*96+k])*st[ST_RSTD2+b*96+k]*x[off]*sv;
  }
  __syncthreads();
  int wv = __builtin_amdgcn_readfirstlane(tid >> 6);
  int lane = tid & 63;
  float acc2[24];
  #pragma unroll
  for (int i=0;i<24;i++) acc2[i]=0.f;
  int o0 = wv*24;

  for (int c=0; c<6; ++c){
    int h0 = c*64 + wv*16;
    float acc1[16];
    #pragma unroll
    for (int i=0;i<16;i++) acc1[i]=0.f;
    for (int k=0;k<96;k++){
      float a = xoS[k*64 + lane];
      const float4* wp = (const float4*)&W1t[(size_t)k*384 + h0];
      float4 w0=wp[0], w1=wp[1], w2=wp[2], w3=wp[3];
      acc1[0]=fmaf(w0.x,a,acc1[0]);  acc1[1]=fmaf(w0.y,a,acc1[1]);
      acc1[2]=fmaf(w0.z,a,acc1[2]);  acc1[3]=fmaf(w0.w,a,acc1[3]);
      acc1[4]=fmaf(w1.x,a,acc1[4]);  acc1[5]=fmaf(w1.y,a,acc1[5]);
      acc1[6]=fmaf(w1.z,a,acc1[6]);  acc1[7]=fmaf(w1.w,a,acc1[7]);
      acc1[8]=fmaf(w2.x,a,acc1[8]);  acc1[9]=fmaf(w2.y,a,acc1[9]);
      acc1[10]=fmaf(w2.z,a,acc1[10]); acc1[11]=fmaf(w2.w,a,acc1[11]);
      acc1[12]=fmaf(w3.x,a,acc1[12]); acc1[13]=fmaf(w3.y,a,acc1[13]);
      acc1[14]=fmaf(w3.z,a,acc1[14]); acc1[15]=fmaf(w3.w,a,acc1[15]);
    }
    if (c) __syncthreads();   // prev chunk's hidS fully consumed
    #pragma unroll
    for (int j=0;j<16;j++)
      hidS[(wv*16+j)*64 + lane] = geluf_(acc1[j] + b1[h0+j]);
    __syncthreads();
    for (int k2=0;k2<64;k2++){
      float a = hidS[k2*64 + lane];
      int kg = c*64 + k2;
      const float4* wp = (const float4*)&W2t[(size_t)kg*96 + o0];
      float4 w0=wp[0], w1=wp[1], w2=wp[2], w3=wp[3], w4=wp[4], w5=wp[5];
      acc2[0]=fmaf(w0.x,a,acc2[0]);  acc2[1]=fmaf(w0.y,a,acc2[1]);
      acc2[2]=fmaf(w0.z,a,acc2[2]);  acc2[3]=fmaf(w0.w,a,acc2[3]);
      acc2[4]=fmaf(w1.x,a,acc2[4]);  acc2[5]=fmaf(w1.y,a,acc2[5]);
      acc2[6]=fmaf(w1.z,a,acc2[6]);  acc2[7]=fmaf(w1.w,a,acc2[7]);
      acc2[8]=fmaf(w2.x,a,acc2[8]);  acc2[9]=fmaf(w2.y,a,acc2[9]);
      acc2[10]=fmaf(w2.z,a,acc2[10]); acc2[11]=fmaf(w2.w,a,acc2[11]);
      acc2[12]=fmaf(w3.x,a,acc2[12]); acc2[13]=fmaf(w3.y,a,acc2[13]);
      acc2[14]=fmaf(w3.z,a,acc2[14]); acc2[15]=fmaf(w3.w,a,acc2[15]);
      acc2[16]=fmaf(w4.x,a,acc2[16]); acc2[17]=fmaf(w4.y,a,acc2[17]);
      acc2[18]=fmaf(w4.z,a,acc2[18]); acc2[19]=fmaf(w4.w,a,acc2[19]);
      acc2[20]=fmaf(w5.x,a,acc2[20]); acc2[21]=fmaf(w5.y,a,acc2[21]);
      acc2[22]=fmaf(w5.z,a,acc2[22]); acc2[23]=fmaf(w5.w,a,acc2[23]);
    }
  }
  #pragma unroll
  for (int j=0;j<24;j++){
    int o = o0 + j;
    size_t off = ((size_t)b*96+o)*NSPA + l0 + lane;
    dout[off] = acc2[j] + b2[o] + x[off];
  }
}

extern "C" void kernel_launch(void* const* d_in, const int* in_sizes, int n_in,
                              void* d_out, int out_size, void* d_ws, size_t ws_size,
                              hipStream_t stream) {
  const float* x        = (const float*)d_in[0];
  const float* c1w      = (const float*)d_in[1];
  const float* c1b      = (const float*)d_in[2];
  const float* c3w      = (const float*)d_in[3];
  const float* c3b      = (const float*)d_in[4];
  const float* gnw      = (const float*)d_in[5];
  const float* gnb      = (const float*)d_in[6];
  const float* in_proj  = (const float*)d_in[7];
  const float* conv1dw  = (const float*)d_in[8];
  const float* conv1db  = (const float*)d_in[9];
  const float* xprojw   = (const float*)d_in[10];
  const float* dtw      = (const float*)d_in[11];
  const float* dtb      = (const float*)d_in[12];
  const float* A_log    = (const float*)d_in[13];
  const float* ssm_D    = (const float*)d_in[14];
  const float* outprojw = (const float*)d_in[15];
  const float* W1       = (const float*)d_in[16];
  const float* b1       = (const float*)d_in[17];
  const float* W2       = (const float*)d_in[18];
  const float* b2       = (const float*)d_in[19];
  float* dout = (float*)d_out;

  float* ws = (float*)d_ws;
  const size_t o_st = 0;
  const size_t o_A  = 65536;
  const size_t o_B  = o_A + 12582912;
  const size_t o_C  = o_B + 12582912;
  const size_t o_D  = o_C + 12582912;
  const size_t o_E  = o_D + 6291456;
  const size_t o_F  = o_E + 6291456;
  float* st    = ws + o_st;
  float* P     = ws + o_A;            // 6,291,456 floats
  float* Hs    = ws + o_A + 6291456;  // 6,291,456 floats
  float* zg_t  = ws + o_B;
  float* xc_t  = ws + o_C;
  float* gated = ws + o_D;
  float* dbl_t = ws + o_D;            // gated dead after sppe_out
  float* x2b   = ws + o_E;
  float* hendb = ws + o_E;            // x2 dead after sppe_out
  float* outb  = ws + o_E;            // hend dead after scanB
  // o_F region: prepped weights + sigmoid gate
  float* W1t   = ws + o_F + 0;        // 36,864
  float* W2t   = ws + o_F + 40960;    // 36,864
  float* Wipt  = ws + o_F + 81920;    // 36,864
  float* xpWt  = ws + o_F + 122880;   // 9,216
  float* Wot   = ws + o_F + 139264;   // 18,432
  float* sigb  = ws + o_F + 200704;   // 524,288
  float* wtb   = st + ST_WT;          // 3,888

  hipMemsetAsync(st, 0, 65536*sizeof(float), stream);

  // --- all weight transposes ---
  k_prep<<<556, 256, 0, stream>>>(c3w, W1, W2, in_proj, xprojw, outprojw,
                                  wtb, W1t, W2t, Wipt, xpWt, Wot);
  // --- SPPE branch + inorm stats ---
  k_stats<<<192, 1024, 0, stream>>>(x, st);
  k_gates<<<16, 128, 0, stream>>>(c1w, c1b, st);
  k_gated<<<192, 1024, 0, stream>>>(x, gated, st);
  k_conv3<<<dim3(4,8,16), 256, 0, stream>>>(x, wtb, c3b, x2b, st);
  k_sppe_out<<<dim3(128,16), 256, 0, stream>>>(gated, x2b, gnw, gnb, st, sigb);
  // --- fused in_proj (inorm) + conv1d + silu -> xc_t, zg_t (halo via LDS) ---
  k_front<<<dim3(512,2), 256, 0, stream>>>(x, Wipt, conv1dw, conv1db,
                                           st, xc_t, zg_t);
  // --- x_proj -> dbl_t token-major [B|C|dt] ---
  k_gemm_xp<<<dim3(512,2), 256, 0, stream>>>(xc_t, xpWt, dbl_t);
  // --- chunked selective scan (dt_proj fused; reg-preload + power-tree dA) ---
  k_scanA<<<dim3(NCH,2), 192, 0, stream>>>(xc_t, dbl_t, dtw, dtb, A_log, P, hendb);
  k_scanB<<<dim3(48,2), 1024, 0, stream>>>(P, hendb, Hs);
  // --- scanC with FUSED out_proj: writes outb directly ---
  k_scanC<<<dim3(NCH,2), 192, 0, stream>>>(xc_t, dbl_t, dtw, dtb, A_log, Hs,
                                           ssm_D, zg_t, Wot, outb);
  // --- stats of out + fully-fused MLP (round-5 proven 256-thr body) ---
  k_stats2<<<192, 256, 0, stream>>>(outb, st);
  k_mlpF<<<dim3(512,2), 256, 0, stream>>>(outb, sigb, st, W1t, b1, W2t, b2, x, dout);
}

// Round 11
// 807.305 us; speedup vs baseline: 1.1231x; 1.1231x over previous
//
#include <hip/hip_runtime.h>
#include <math.h>

#define NSPA 32768           // 32*32*32 spatial positions = L
#define TCH 32               // scan chunk length
#define NCH 1024             // number of chunks = NSPA/TCH
#define EPS 1e-5f

// ---- stats arena offsets (floats, within d_ws[0..65535]) ----
#define ST_MEAN   0      // 192
#define ST_RSTD   192    // 192
#define ST_GM     384    // 192
#define ST_GRSTD  576    // 192
#define ST_X2SUM  768    // 192
#define ST_XH     1024   // 192*32
#define ST_XW     7168   // 192*32
#define ST_XD     13312  // 192*32
#define ST_GATE   19456  // 16*12*96 = 18432
#define ST_MEAN2  38400  // 192
#define ST_RSTD2  38592  // 192
#define ST_WT     40960  // 3888: conv3 weights transposed [ci][tap][co]

__device__ __forceinline__ float sigmoidf_(float x){ return 1.f/(1.f+__expf(-x)); }
__device__ __forceinline__ float siluf_(float x){ return x/(1.f+__expf(-x)); }
__device__ __forceinline__ float geluf_(float x){ return 0.5f*x*(1.f+erff(x*0.70710678118654752f)); }
__device__ __forceinline__ float softplusf_(float x){ return fmaxf(x,0.f) + log1pf(__expf(-fabsf(x))); }

// ============ K0: all weight transposes in one kernel ============
// idx ranges: wt 3888 | W1t 36864 | W2t 36864 | Wipt 36864 | xpWt 9216 | Wot 18432
__global__ void k_prep(const float* __restrict__ c3w, const float* __restrict__ W1,
                       const float* __restrict__ W2, const float* __restrict__ Wip,
                       const float* __restrict__ xpw, const float* __restrict__ Wout,
                       float* __restrict__ wt, float* __restrict__ W1t,
                       float* __restrict__ W2t, float* __restrict__ Wipt,
                       float* __restrict__ xpWt, float* __restrict__ Wot) {
  int idx = blockIdx.x*256 + threadIdx.x;
  if (idx < 3888) {
    int co = idx/324, r = idx%324;
    wt[r*12+co] = c3w[co*324+r];
  } else if (idx < 40752) {
    int i = idx-3888; int k = i/384, h = i%384;
    W1t[i] = W1[(size_t)h*96+k];
  } else if (idx < 77616) {
    int i = idx-40752; int k = i/96, o = i%96;
    W2t[i] = W2[(size_t)o*384+k];
  } else if (idx < 114480) {
    int i = idx-77616; int k = i/384, r = i%384;
    Wipt[i] = Wip[(size_t)r*96+k];
  } else if (idx < 123696) {
    int i = idx-114480; int e = i/48, o = i%48;
    float v = 0.f;
    if (o < 38) { int row = (o<32)? (o+6) : (o-32); v = xpw[(size_t)row*192+e]; }
    xpWt[i] = v;
  } else if (idx < 142128) {
    int i = idx-123696; int e = i/96, o = i%96;
    Wot[i] = Wout[(size_t)o*192+e];
  }
}

// ============ K1: per-(b,c) instance-norm stats + SPPE pooled means ============
// grid 192, block 1024
__global__ void k_stats(const float* __restrict__ x, float* __restrict__ st) {
  int bc = blockIdx.x;
  int t = threadIdx.x;
  __shared__ float xh_s[32], xw_s[32], xd_s[32], red[16], red2[16];
  if (t < 32) { xh_s[t]=0.f; xw_s[t]=0.f; xd_s[t]=0.f; }
  __syncthreads();
  const float* px = x + (size_t)bc*NSPA;
  float s=0.f, s2=0.f;
  for (int it=0; it<32; ++it) {
    float v = px[it*1024 + t];
    s += v; s2 += v*v;
    float wv = v;
    #pragma unroll
    for (int m=32;m>=1;m>>=1) wv += __shfl_xor(wv,m);
    if ((t&63)==0) atomicAdd(&xh_s[it], wv);
  }
  atomicAdd(&xw_s[(t>>5)&31], s);
  atomicAdd(&xd_s[t&31], s);
  float rs=s, rs2=s2;
  #pragma unroll
  for (int m=32;m>=1;m>>=1){ rs += __shfl_xor(rs,m); rs2 += __shfl_xor(rs2,m); }
  if ((t&63)==0){ red[t>>6]=rs; red2[t>>6]=rs2; }
  __syncthreads();
  if (t==0){
    float S=0.f,S2=0.f;
    for (int w=0;w<16;w++){ S+=red[w]; S2+=red2[w]; }
    float mn = S/(float)NSPA;
    float var = S2/(float)NSPA - mn*mn;
    st[ST_MEAN+bc] = mn;
    st[ST_RSTD+bc] = rsqrtf(var+EPS);
  }
  if (t<32){
    st[ST_XH + bc*32 + t] = xh_s[t]*(1.f/1024.f);
    st[ST_XW + bc*32 + t] = xw_s[t]*(1.f/1024.f);
    st[ST_XD + bc*32 + t] = xd_s[t]*(1.f/1024.f);
  }
}

// ============ K2: SPPE 1x1 conv on pooled vectors -> sigmoid gates ============
__global__ void k_gates(const float* __restrict__ c1w, const float* __restrict__ c1b,
                        float* __restrict__ st) {
  int bg = blockIdx.x; int b = bg>>3; int g = bg&7;
  for (int i = threadIdx.x; i < 12*96; i += 128) {
    int co = i/96, pos = i%96;
    float acc = c1b[co];
    for (int cg=0; cg<12; ++cg) {
      int bc = b*96 + g*12 + cg;
      float hv;
      if (pos < 32)      hv = st[ST_XH + bc*32 + pos];
      else if (pos < 64) hv = st[ST_XW + bc*32 + pos-32];
      else               hv = st[ST_XD + bc*32 + pos-64];
      acc += c1w[co*12+cg]*hv;
    }
    st[ST_GATE + bg*1152 + i] = sigmoidf_(acc);
  }
}

// ============ K3: group-norm stats of gated (gated NOT materialized) ============
// gated = x*gh*gw*gd recomputed later in sppe_out; here only sum/sumsq.
__global__ void k_gated(const float* __restrict__ x, float* __restrict__ st) {
  int bc = blockIdx.x; int bg = bc/12; int cg = bc%12;
  int t = threadIdx.x;
  const float* gate = st + ST_GATE + bg*1152 + cg*96;
  float gw = gate[32 + (t>>5)];
  float gd = gate[64 + (t&31)];
  const float* px = x + (size_t)bc*NSPA;
  __shared__ float red[16], red2[16];
  float s=0.f, s2=0.f;
  for (int it=0; it<32; ++it) {
    float gh = gate[it];
    float v = px[it*1024+t]*gh*gw*gd;
    s += v; s2 += v*v;
  }
  #pragma unroll
  for (int m=32;m>=1;m>>=1){ s += __shfl_xor(s,m); s2 += __shfl_xor(s2,m); }
  if ((t&63)==0){ red[t>>6]=s; red2[t>>6]=s2; }
  __syncthreads();
  if (t==0){
    float S=0.f,S2=0.f;
    for (int w=0;w<16;w++){ S+=red[w]; S2+=red2[w]; }
    float mn = S/(float)NSPA;
    float var = S2/(float)NSPA - mn*mn;
    st[ST_GM+bc] = mn;
    st[ST_GRSTD+bc] = rsqrtf(var+EPS);
  }
}

// ============ K4: grouped 3x3x3 conv via LDS ring-slabs + per-channel sums ============
// grid (4, 8, 16) = (2x2 wd-tiles, 8 h-chunks of 4, bg); block 256 (16w x 16d).
__global__ void k_conv3(const float* __restrict__ x, const float* __restrict__ wt,
                        const float* __restrict__ c3b, float* __restrict__ x2,
                        float* __restrict__ st) {
  __shared__ float sl[3][12*324];
  __shared__ float ssum[12];
  int bg = blockIdx.z;
  int w0 = (blockIdx.x & 1)*16, d0 = (blockIdx.x >> 1)*16;
  int h0 = blockIdx.y*4;
  int tid = threadIdx.x;
  if (tid < 12) ssum[tid] = 0.f;

  const float* xb = x + (size_t)bg*12*NSPA;

  auto load_slab = [&](int hh, int s){
    for (int i=tid; i<3888; i+=256){
      int ci = i/324, r = i%324;
      int lw = r/18, ld = r%18;
      int gw = w0-1+lw, gd = d0-1+ld;
      float v = 0.f;
      if ((unsigned)hh<32u && (unsigned)gw<32u && (unsigned)gd<32u)
        v = xb[(size_t)ci*NSPA + hh*1024 + gw*32 + gd];
      sl[s][i] = v;
    }
  };

  load_slab(h0-1, ((h0-1)%3+3)%3);
  load_slab(h0,   h0%3);
  load_slab(h0+1, (h0+1)%3);
  __syncthreads();

  int w = tid>>4, d = tid&15;
  int base_wd = w*18 + d;
  float b0v=c3b[0],b1v=c3b[1],b2v=c3b[2],b3v=c3b[3],b4v=c3b[4],b5v=c3b[5],
        b6v=c3b[6],b7v=c3b[7],b8v=c3b[8],b9v=c3b[9],b10v=c3b[10],b11v=c3b[11];

  for (int it=0; it<4; ++it){
    int h = h0 + it;
    const float* sm1 = sl[((h-1)%3+3)%3];
    const float* s00 = sl[h%3];
    const float* sp1 = sl[(h+1)%3];
    float acc[12];
    acc[0]=b0v; acc[1]=b1v; acc[2]=b2v; acc[3]=b3v; acc[4]=b4v; acc[5]=b5v;
    acc[6]=b6v; acc[7]=b7v; acc[8]=b8v; acc[9]=b9v; acc[10]=b10v; acc[11]=b11v;
    for (int ci=0; ci<12; ++ci){
      const float* w_ci = wt + ci*324;
      #pragma unroll
      for (int kh=0;kh<3;kh++){
        const float* sp = (kh==0)? sm1 : ((kh==1)? s00 : sp1);
        const float* srow = sp + ci*324 + base_wd;
        #pragma unroll
        for (int kw=0;kw<3;kw++){
          #pragma unroll
          for (int kd=0;kd<3;kd++){
            float v = srow[kw*18 + kd];
            const float4* wp = (const float4*)(w_ci + (kh*9+kw*3+kd)*12);
            float4 wa = wp[0], wb = wp[1], wc = wp[2];
            acc[0]=fmaf(wa.x,v,acc[0]); acc[1]=fmaf(wa.y,v,acc[1]);
            acc[2]=fmaf(wa.z,v,acc[2]); acc[3]=fmaf(wa.w,v,acc[3]);
            acc[4]=fmaf(wb.x,v,acc[4]); acc[5]=fmaf(wb.y,v,acc[5]);
            acc[6]=fmaf(wb.z,v,acc[6]); acc[7]=fmaf(wb.w,v,acc[7]);
            acc[8]=fmaf(wc.x,v,acc[8]); acc[9]=fmaf(wc.y,v,acc[9]);
            acc[10]=fmaf(wc.z,v,acc[10]); acc[11]=fmaf(wc.w,v,acc[11]);
          }
        }
      }
    }
    int l = h*1024 + (w0+w)*32 + (d0+d);
    #pragma unroll
    for (int co=0;co<12;co++){
      float r = acc[co];
      x2[(size_t)(bg*12+co)*NSPA + l] = r;
      float rv = r;
      #pragma unroll
      for (int m=32;m>=1;m>>=1) rv += __shfl_xor(rv,m);
      if ((tid&63)==0) atomicAdd(&ssum[co], rv);
    }
    __syncthreads();
    if (it<3){
      load_slab(h+2, (h+2)%3);
      __syncthreads();
    }
  }
  if (tid<12) atomicAdd(&st[ST_X2SUM + bg*12 + tid], ssum[tid]);
}

// ============ K5: SPPE attention -> sigmoid gate; gated recomputed from x ========
__global__ void k_sppe_out(const float* __restrict__ x,
                           const float* __restrict__ x2, const float* __restrict__ gnw,
                           const float* __restrict__ gnb, const float* __restrict__ st,
                           float* __restrict__ sigb) {
  int bg = blockIdx.y; int b = bg>>3; int g = bg&7;
  __shared__ float x11s[12], alphas[12], betasum_s;
  __shared__ float gateS[1152];
  for (int i=threadIdx.x;i<1152;i+=256) gateS[i] = st[ST_GATE + bg*1152 + i];
  if (threadIdx.x==0){
    float m1=-1e30f, m2=-1e30f;
    float mu2[12];
    for (int cg=0;cg<12;cg++){
      int bc=b*96+g*12+cg;
      mu2[cg] = st[ST_X2SUM+bc]*(1.f/(float)NSPA);
      m1 = fmaxf(m1, gnb[cg]); m2 = fmaxf(m2, mu2[cg]);
    }
    float e1[12], e2[12]; float s1=0.f, s2=0.f;
    for (int cg=0;cg<12;cg++){ e1[cg]=expf(gnb[cg]-m1); s1+=e1[cg];
                               e2[cg]=expf(mu2[cg]-m2); s2+=e2[cg]; }
    float bs=0.f;
    for (int cg=0;cg<12;cg++){
      int bc=b*96+g*12+cg;
      float x11 = e1[cg]/s1;
      float x21 = e2[cg]/s2;
      x11s[cg]=x11;
      float gr = st[ST_GRSTD+bc], gm = st[ST_GM+bc];
      alphas[cg] = x21*gr*gnw[cg];
      bs += x21*(gnb[cg] - gm*gr*gnw[cg]);
    }
    betasum_s = bs;
  }
  __syncthreads();
  int l = blockIdx.x*256 + threadIdx.x;
  int h = l>>10, w8 = (l>>5)&31, d = l&31;
  float wsum = betasum_s;
  int bc0 = b*96+g*12;
  for (int cg=0;cg<12;cg++){
    size_t off = (size_t)(bc0+cg)*NSPA + l;
    // gated recomputed exactly as k_gated did: x*gh*gw*gd
    float gv = x[off]*gateS[cg*96+h]*gateS[cg*96+32+w8]*gateS[cg*96+64+d];
    wsum += x11s[cg]*x2[off] + alphas[cg]*gv;
  }
  sigb[(size_t)bg*NSPA + l] = sigmoidf_(wsum);
}

// ============ K6: FUSED in_proj (inorm folded) + causal conv1d + silu ============
// grid (512,2), block 256.
__global__ void k_front(const float* __restrict__ x, const float* __restrict__ Wipt,
                        const float* __restrict__ cw, const float* __restrict__ cb,
                        const float* __restrict__ st,
                        float* __restrict__ xc_t, float* __restrict__ zg_t) {
  __shared__ float As[96*64];     // normalized x tile [k][l]
  __shared__ float outS[48*65];   // per-phase output staging [row][l] (padded)
  __shared__ float haloS[3*192];  // xm at tokens l0-3..l0-1
  __shared__ float xhS[3*96];     // normalized x at halo tokens [j][k]
  int b = blockIdx.y; int l0 = blockIdx.x*64; int tid = threadIdx.x;
  const float* mean = st + ST_MEAN + b*96;
  const float* rstd = st + ST_RSTD + b*96;
  for (int i=tid;i<96*64;i+=256){
    int k=i>>6, l=i&63;
    As[i] = (x[((size_t)b*96+k)*NSPA + l0+l]-mean[k])*rstd[k];
  }
  for (int i=tid;i<288;i+=256){
    int j=i/96, k=i%96;
    int t = l0-3+j;
    xhS[i] = (t>=0) ? (x[((size_t)b*96+k)*NSPA + t]-mean[k])*rstd[k] : 0.f;
  }
  __syncthreads();
  for (int i=tid;i<576;i+=256){
    int j=i/192, e=i%192;
    const float* xh = xhS + j*96;
    float s = 0.f;
    for (int k=0;k<96;k++) s = fmaf(Wipt[(size_t)k*384 + e], xh[k], s);
    haloS[j*192+e] = s;
  }
  __syncthreads();
  int wv = __builtin_amdgcn_readfirstlane(tid>>6);
  int lane = tid&63;
  for (int p=0;p<8;++p){
    int r0 = p*48 + wv*12;
    float acc[12];
    #pragma unroll
    for (int j=0;j<12;j++) acc[j]=0.f;
    for (int k=0;k<96;k++){
      float a = As[k*64+lane];
      const float4* wp = (const float4*)&Wipt[(size_t)k*384 + r0];
      float4 w0=wp[0],w1=wp[1],w2=wp[2];
      acc[0]=fmaf(w0.x,a,acc[0]);  acc[1]=fmaf(w0.y,a,acc[1]);
      acc[2]=fmaf(w0.z,a,acc[2]);  acc[3]=fmaf(w0.w,a,acc[3]);
      acc[4]=fmaf(w1.x,a,acc[4]);  acc[5]=fmaf(w1.y,a,acc[5]);
      acc[6]=fmaf(w1.z,a,acc[6]);  acc[7]=fmaf(w1.w,a,acc[7]);
      acc[8]=fmaf(w2.x,a,acc[8]);  acc[9]=fmaf(w2.y,a,acc[9]);
      acc[10]=fmaf(w2.z,a,acc[10]); acc[11]=fmaf(w2.w,a,acc[11]);
    }
    if (p) __syncthreads();
    if (p < 4){
      #pragma unroll
      for (int j=0;j<12;j++){
        int e = r0 + j;
        float v = acc[j];
        float vm1 = __shfl_up(v,1);
        float vm2 = __shfl_up(v,2);
        float vm3 = __shfl_up(v,3);
        if (lane==0) vm1 = haloS[2*192+e];
        if (lane<=1) vm2 = haloS[(1+lane)*192+e];
        if (lane<=2) vm3 = haloS[(0+lane)*192+e];
        float4 w4 = *(const float4*)&cw[e*4];
        float r_ = cb[e] + w4.x*vm3 + w4.y*vm2 + w4.z*vm1 + w4.w*v;
        outS[(wv*12+j)*65 + lane] = siluf_(r_);
      }
    } else {
      #pragma unroll
      for (int j=0;j<12;j++) outS[(wv*12+j)*65 + lane] = acc[j];
    }
    __syncthreads();
    float* dst = (p<4) ? xc_t : zg_t;
    int e0 = (p<4) ? p*48 : (p-4)*48;
    for (int i=tid; i<64*12; i+=256){
      int l = i/12, q = i%12;
      float4 v;
      v.x = outS[(q*4+0)*65 + l];
      v.y = outS[(q*4+1)*65 + l];
      v.z = outS[(q*4+2)*65 + l];
      v.w = outS[(q*4+3)*65 + l];
      *(float4*)&dst[((size_t)b*NSPA + l0+l)*192 + e0 + q*4] = v;
    }
  }
}

// ============ K7: x_proj GEMM, uniform s_load weights, staged flush ============
__global__ void k_gemm_xp(const float* __restrict__ A, const float* __restrict__ xpWt,
                          float* __restrict__ dbl_t) {
  __shared__ float As[96*65];
  __shared__ float dblS[48*65];
  int b = blockIdx.y; int l0 = blockIdx.x*64; int tid = threadIdx.x;
  int wv = __builtin_amdgcn_readfirstlane(tid>>6);
  int lane = tid&63;
  int o0 = wv*12;
  float acc[12];
  #pragma unroll
  for (int j=0;j<12;j++) acc[j]=0.f;
  for (int h=0;h<2;++h){
    if (h) __syncthreads();
    for (int i=tid;i<64*24;i+=256){
      int l=i/24, q=i%24;
      float4 v = *(const float4*)&A[((size_t)b*NSPA + l0+l)*192 + h*96 + q*4];
      As[(q*4+0)*65+l]=v.x; As[(q*4+1)*65+l]=v.y;
      As[(q*4+2)*65+l]=v.z; As[(q*4+3)*65+l]=v.w;
    }
    __syncthreads();
    for (int k=0;k<96;k++){
      float a = As[k*65+lane];
      const float4* wp = (const float4*)&xpWt[(size_t)(h*96+k)*48 + o0];
      float4 w0=wp[0],w1=wp[1],w2=wp[2];
      acc[0]=fmaf(w0.x,a,acc[0]);  acc[1]=fmaf(w0.y,a,acc[1]);
      acc[2]=fmaf(w0.z,a,acc[2]);  acc[3]=fmaf(w0.w,a,acc[3]);
      acc[4]=fmaf(w1.x,a,acc[4]);  acc[5]=fmaf(w1.y,a,acc[5]);
      acc[6]=fmaf(w1.z,a,acc[6]);  acc[7]=fmaf(w1.w,a,acc[7]);
      acc[8]=fmaf(w2.x,a,acc[8]);  acc[9]=fmaf(w2.y,a,acc[9]);
      acc[10]=fmaf(w2.z,a,acc[10]); acc[11]=fmaf(w2.w,a,acc[11]);
    }
  }
  __syncthreads();
  #pragma unroll
  for (int j=0;j<12;j++) dblS[(o0+j)*65 + lane] = acc[j];
  __syncthreads();
  for (int i=tid;i<64*10;i+=256){
    int l=i/10, q=i%10;
    float4 v;
    v.x = dblS[(q*4+0)*65+l]; v.y = dblS[(q*4+1)*65+l];
    v.z = dblS[(q*4+2)*65+l]; v.w = dblS[(q*4+3)*65+l];
    *(float4*)&dbl_t[((size_t)b*NSPA + l0+l)*40 + q*4] = v;
  }
}

// ============ scan phase A: lane = e, 16 states in registers (round-9 body) =====
// Fast path: dA via power tree (1 exp); Pp via S=sum(dte) -> one final exp.
__global__ void k_scanA(const float* __restrict__ xc_t, const float* __restrict__ dbl_t,
                        const float* __restrict__ dtw, const float* __restrict__ dtb,
                        const float* __restrict__ A_log,
                        float* __restrict__ P, float* __restrict__ hend) {
  int b = blockIdx.y, ch = blockIdx.x; int e = threadIdx.x;
  float An[16];
  #pragma unroll
  for (int n=0;n<16;n++) An[n] = -__expf(A_log[e*16+n]);
  float An0 = An[0];
  bool fast = true;
  #pragma unroll
  for (int n=0;n<16;n++)
    fast = fast && (fabsf(An[n] - (float)(n+1)*An0) <= 1e-4f*(float)(n+1));
  float wdt[6];
  #pragma unroll
  for (int j=0;j<6;j++) wdt[j]=dtw[e*6+j];
  float bdt = dtb[e];
  const float* drow = dbl_t + ((size_t)b*NSPA + (size_t)ch*TCH)*40;
  const float* xrow = xc_t + ((size_t)b*NSPA + (size_t)ch*TCH)*192 + e;
  float h[16], Pp[16];
  #pragma unroll
  for (int n=0;n<16;n++){ h[n]=0.f; Pp[n]=1.f; }
  if (fast){
    float Sdt = 0.f;
    for (int l=0;l<TCH;l++){
      const float* u = drow + l*40;
      float4 b0=*(const float4*)(u+0), b1=*(const float4*)(u+4),
             b2=*(const float4*)(u+8), b3=*(const float4*)(u+12);
      float4 d4=*(const float4*)(u+32);
      float2 d2=*(const float2*)(u+36);
      float x = xrow[(size_t)l*192];
      float pre = bdt + wdt[0]*d4.x + wdt[1]*d4.y + wdt[2]*d4.z
                      + wdt[3]*d4.w + wdt[4]*d2.x + wdt[5]*d2.y;
      float dte = softplusf_(pre);
      Sdt += dte;
      float dtx = dte*x;
      float Bv[16] = {b0.x,b0.y,b0.z,b0.w, b1.x,b1.y,b1.z,b1.w,
                      b2.x,b2.y,b2.z,b2.w, b3.x,b3.y,b3.z,b3.w};
      float r1 = __expf(dte*An0);
      float r2=r1*r1, r3=r2*r1, r4=r2*r2;
      float r5=r4*r1, r6=r4*r2, r7=r4*r3, r8=r4*r4;
      float av[16] = {r1,r2,r3,r4,r5,r6,r7,r8,
                      r8*r1,r8*r2,r8*r3,r8*r4,r8*r5,r8*r6,r8*r7,r8*r8};
      #pragma unroll
      for (int n=0;n<16;n++){
        h[n] = h[n]*av[n] + dtx*Bv[n];
      }
    }
    float R1 = __expf(Sdt*An0);
    float R2=R1*R1, R3=R2*R1, R4=R2*R2;
    float R5=R4*R1, R6=R4*R2, R7=R4*R3, R8=R4*R4;
    Pp[0]=R1; Pp[1]=R2; Pp[2]=R3; Pp[3]=R4;
    Pp[4]=R5; Pp[5]=R6; Pp[6]=R7; Pp[7]=R8;
    Pp[8]=R8*R1; Pp[9]=R8*R2; Pp[10]=R8*R3; Pp[11]=R8*R4;
    Pp[12]=R8*R5; Pp[13]=R8*R6; Pp[14]=R8*R7; Pp[15]=R8*R8;
  } else {
    for (int l=0;l<TCH;l++){
      const float* u = drow + l*40;
      float4 b0=*(const float4*)(u+0), b1=*(const float4*)(u+4),
             b2=*(const float4*)(u+8), b3=*(const float4*)(u+12);
      float4 d4=*(const float4*)(u+32);
      float2 d2=*(const float2*)(u+36);
      float x = xrow[(size_t)l*192];
      float pre = bdt + wdt[0]*d4.x + wdt[1]*d4.y + wdt[2]*d4.z
                      + wdt[3]*d4.w + wdt[4]*d2.x + wdt[5]*d2.y;
      float dte = softplusf_(pre);
      float dtx = dte*x;
      float Bv[16] = {b0.x,b0.y,b0.z,b0.w, b1.x,b1.y,b1.z,b1.w,
                      b2.x,b2.y,b2.z,b2.w, b3.x,b3.y,b3.z,b3.w};
      #pragma unroll
      for (int n=0;n<16;n++){
        float a = __expf(dte*An[n]);
        Pp[n] *= a;
        h[n] = h[n]*a + dtx*Bv[n];
      }
    }
  }
  size_t o = (((size_t)b*NCH+ch)*192+e)*16;
  #pragma unroll
  for (int q=0;q<4;q++){
    float4 rp; rp.x=Pp[q*4+0]; rp.y=Pp[q*4+1]; rp.z=Pp[q*4+2]; rp.w=Pp[q*4+3];
    *(float4*)&P[o+q*4] = rp;
    float4 rh; rh.x=h[q*4+0]; rh.y=h[q*4+1]; rh.z=h[q*4+2]; rh.w=h[q*4+3];
    *(float4*)&hend[o+q*4] = rh;
  }
}

// ============ scan phase B: PARALLEL segmented inter-chunk combine ============
__global__ void k_scanB(const float* __restrict__ P, const float* __restrict__ hend,
                        float* __restrict__ Hs) {
  __shared__ float sP[16][64], sH[16][64];
  int b = blockIdx.y;
  int rl = threadIdx.x & 63;
  int cg = threadIdx.x >> 6;               // 0..15
  int r  = blockIdx.x*64 + rl;             // 0..3071 within batch
  size_t base = (size_t)b*NCH*3072 + r;
  int c0 = cg*64;
  float Pl = 1.f, hl = 0.f;
  for (int c=c0; c<c0+64; ++c){
    size_t idx = base + (size_t)c*3072;
    float Pc = P[idx], Hc = hend[idx];
    hl = fmaf(Pc, hl, Hc);
    Pl *= Pc;
  }
  sP[cg][rl] = Pl; sH[cg][rl] = hl;
  __syncthreads();
  float H = 0.f;
  for (int g=0; g<cg; ++g) H = fmaf(sP[g][rl], H, sH[g][rl]);
  for (int c=c0; c<c0+64; ++c){
    size_t idx = base + (size_t)c*3072;
    float Pc = P[idx], Hc = hend[idx];
    Hs[idx] = H;
    H = fmaf(Pc, H, Hc);
  }
}

// ============ scan phase C: round-9 proven body (exp tree, rolled loop) ==========
// y kept in LDS; out_proj in-block, e-major coalesced stores. grid (NCH, 2), 192.
__global__ void k_scanC(const float* __restrict__ xc_t, const float* __restrict__ dbl_t,
                        const float* __restrict__ dtw, const float* __restrict__ dtb,
                        const float* __restrict__ A_log, const float* __restrict__ Hs,
                        const float* __restrict__ ssm_D, const float* __restrict__ zg_t,
                        const float* __restrict__ Wot, float* __restrict__ out) {
  __shared__ float yS[32*193];   // [l][e], pad 193 -> conflict-free both phases
  int b = blockIdx.y, ch = blockIdx.x; int e = threadIdx.x;
  float An[16];
  #pragma unroll
  for (int n=0;n<16;n++) An[n] = -__expf(A_log[e*16+n]);
  float An0 = An[0];
  bool fast = true;
  #pragma unroll
  for (int n=0;n<16;n++)
    fast = fast && (fabsf(An[n] - (float)(n+1)*An0) <= 1e-4f*(float)(n+1));
  float wdt[6];
  #pragma unroll
  for (int j=0;j<6;j++) wdt[j]=dtw[e*6+j];
  float bdt = dtb[e];
  float Dv = ssm_D[e];
  const float* drow = dbl_t + ((size_t)b*NSPA + (size_t)ch*TCH)*40;
  const float* xrow = xc_t + ((size_t)b*NSPA + (size_t)ch*TCH)*192 + e;
  const float* zrow = zg_t + ((size_t)b*NSPA + (size_t)ch*TCH)*192 + e;
  float h[16];
  size_t ho = (((size_t)b*NCH+ch)*192+e)*16;
  #pragma unroll
  for (int q=0;q<4;q++){
    float4 hv = *(const float4*)&Hs[ho+q*4];
    h[q*4+0]=hv.x; h[q*4+1]=hv.y; h[q*4+2]=hv.z; h[q*4+3]=hv.w;
  }
  if (fast){
    for (int l=0;l<TCH;l++){
      const float* u = drow + l*40;
      float4 b0=*(const float4*)(u+0), b1=*(const float4*)(u+4),
             b2=*(const float4*)(u+8), b3=*(const float4*)(u+12);
      float4 c0=*(const float4*)(u+16), c1=*(const float4*)(u+20),
             c2=*(const float4*)(u+24), c3=*(const float4*)(u+28);
      float4 d4=*(const float4*)(u+32);
      float2 d2=*(const float2*)(u+36);
      float x = xrow[(size_t)l*192];
      float z = zrow[(size_t)l*192];
      float pre = bdt + wdt[0]*d4.x + wdt[1]*d4.y + wdt[2]*d4.z
                      + wdt[3]*d4.w + wdt[4]*d2.x + wdt[5]*d2.y;
      float dte = softplusf_(pre);
      float dtx = dte*x;
      float Bv[16] = {b0.x,b0.y,b0.z,b0.w, b1.x,b1.y,b1.z,b1.w,
                      b2.x,b2.y,b2.z,b2.w, b3.x,b3.y,b3.z,b3.w};
      float Cv[16] = {c0.x,c0.y,c0.z,c0.w, c1.x,c1.y,c1.z,c1.w,
                      c2.x,c2.y,c2.z,c2.w, c3.x,c3.y,c3.z,c3.w};
      float r1 = __expf(dte*An0);
      float r2=r1*r1, r3=r2*r1, r4=r2*r2;
      float r5=r4*r1, r6=r4*r2, r7=r4*r3, r8=r4*r4;
      float av[16] = {r1,r2,r3,r4,r5,r6,r7,r8,
                      r8*r1,r8*r2,r8*r3,r8*r4,r8*r5,r8*r6,r8*r7,r8*r8};
      float yp = 0.f;
      #pragma unroll
      for (int n=0;n<16;n++){
        h[n] = h[n]*av[n] + dtx*Bv[n];
        yp += h[n]*Cv[n];
      }
      yS[l*193 + e] = (yp + x*Dv)*siluf_(z);
    }
  } else {
    for (int l=0;l<TCH;l++){
      const float* u = drow + l*40;
      float4 b0=*(const float4*)(u+0), b1=*(const float4*)(u+4),
             b2=*(const float4*)(u+8), b3=*(const float4*)(u+12);
      float4 c0=*(const float4*)(u+16), c1=*(const float4*)(u+20),
             c2=*(const float4*)(u+24), c3=*(const float4*)(u+28);
      float4 d4=*(const float4*)(u+32);
      float2 d2=*(const float2*)(u+36);
      float x = xrow[(size_t)l*192];
      float z = zrow[(size_t)l*192];
      float pre = bdt + wdt[0]*d4.x + wdt[1]*d4.y + wdt[2]*d4.z
                      + wdt[3]*d4.w + wdt[4]*d2.x + wdt[5]*d2.y;
      float dte = softplusf_(pre);
      float dtx = dte*x;
      float Bv[16] = {b0.x,b0.y,b0.z,b0.w, b1.x,b1.y,b1.z,b1.w,
                      b2.x,b2.y,b2.z,b2.w, b3.x,b3.y,b3.z,b3.w};
      float Cv[16] = {c0.x,c0.y,c0.z,c0.w, c1.x,c1.y,c1.z,c1.w,
                      c2.x,c2.y,c2.z,c2.w, c3.x,c3.y,c3.z,c3.w};
      float yp = 0.f;
      #pragma unroll
      for (int n=0;n<16;n++){
        float a = __expf(dte*An[n]);
        h[n] = h[n]*a + dtx*Bv[n];
        yp += h[n]*Cv[n];
      }
      yS[l*193 + e] = (yp + x*Dv)*siluf_(z);
    }
  }
  __syncthreads();
  // ---- out_proj: thread (l = tid&31, og = tid>>5) computes 16 outputs ----
  int tl = e & 31;          // token within chunk
  int og = e >> 5;          // 0..5
  int o0 = og*16;
  float acc[16];
  #pragma unroll
  for (int i=0;i<16;i++) acc[i]=0.f;
  const float* yrowS = yS + tl*193;
  for (int k=0;k<192;k++){
    float a = yrowS[k];
    const float4* wp = (const float4*)&Wot[(size_t)k*96 + o0];
    float4 w0=wp[0], w1=wp[1], w2=wp[2], w3=wp[3];
    acc[0]=fmaf(w0.x,a,acc[0]);  acc[1]=fmaf(w0.y,a,acc[1]);
    acc[2]=fmaf(w0.z,a,acc[2]);  acc[3]=fmaf(w0.w,a,acc[3]);
    acc[4]=fmaf(w1.x,a,acc[4]);  acc[5]=fmaf(w1.y,a,acc[5]);
    acc[6]=fmaf(w1.z,a,acc[6]);  acc[7]=fmaf(w1.w,a,acc[7]);
    acc[8]=fmaf(w2.x,a,acc[8]);  acc[9]=fmaf(w2.y,a,acc[9]);
    acc[10]=fmaf(w2.z,a,acc[10]); acc[11]=fmaf(w2.w,a,acc[11]);
    acc[12]=fmaf(w3.x,a,acc[12]); acc[13]=fmaf(w3.y,a,acc[13]);
    acc[14]=fmaf(w3.z,a,acc[14]); acc[15]=fmaf(w3.w,a,acc[15]);
  }
  int lbase = ch*TCH + tl;
  #pragma unroll
  for (int j=0;j<16;j++){
    out[((size_t)b*96 + o0+j)*NSPA + lbase] = acc[j];
  }
}

// ============ K15: instance-norm stats of `out` (round-1 proven) ============
__global__ void k_stats2(const float* __restrict__ outb, float* __restrict__ st) {
  int bc = blockIdx.x; int t = threadIdx.x;
  const float* p = outb + (size_t)bc*NSPA;
  float s=0.f, s2=0.f;
  for (int i=t;i<NSPA;i+=256){ float v=p[i]; s+=v; s2+=v*v; }
  __shared__ float red[4], red2[4];
  #pragma unroll
  for (int m=32;m>=1;m>>=1){ s += __shfl_xor(s,m); s2 += __shfl_xor(s2,m); }
  if ((t&63)==0){ red[t>>6]=s; red2[t>>6]=s2; }
  __syncthreads();
  if (t==0){
    float S=red[0]+red[1]+red[2]+red[3];
    float S2=red2[0]+red2[1]+red2[2]+red2[3];
    float mn=S/(float)NSPA; float var=S2/(float)NSPA-mn*mn;
    st[ST_MEAN2+bc]=mn; st[ST_RSTD2+bc]=rsqrtf(var+EPS);
  }
}

// ============ K16: FUSED MLP (round-5 proven: 256 thr, 6 chunks of 64) ==========
__global__ void k_mlpF(const float* __restrict__ outb, const float* __restrict__ sigb,
                       const float* __restrict__ st,
                       const float* __restrict__ W1t, const float* __restrict__ b1,
                       const float* __restrict__ W2t, const float* __restrict__ b2,
                       const float* __restrict__ x, float* __restrict__ dout) {
  __shared__ float xoS[96*64];
  __shared__ float hidS[64*64];
  int b = blockIdx.y; int l0 = blockIdx.x*64; int tid = threadIdx.x;
  for (int i=tid;i<96*64;i+=256){
    int k=i>>6, l=i&63;
    size_t off = ((size_t)b*96+k)*NSPA + l0+l;
    float sv = sigb[((size_t)(b*8 + k/12))*NSPA + l0+l];
    xoS[i] = (outb[off]-st[ST_MEAN2+b*96+k])*st[ST_RSTD2+b*96+k]*x[off]*sv;
  }
  __syncthreads();
  int wv = __builtin_amdgcn_readfirstlane(tid >> 6);
  int lane = tid & 63;
  float acc2[24];
  #pragma unroll
  for (int i=0;i<24;i++) acc2[i]=0.f;
  int o0 = wv*24;

  for (int c=0; c<6; ++c){
    int h0 = c*64 + wv*16;
    float acc1[16];
    #pragma unroll
    for (int i=0;i<16;i++) acc1[i]=0.f;
    for (int k=0;k<96;k++){
      float a = xoS[k*64 + lane];
      const float4* wp = (const float4*)&W1t[(size_t)k*384 + h0];
      float4 w0=wp[0], w1=wp[1], w2=wp[2], w3=wp[3];
      acc1[0]=fmaf(w0.x,a,acc1[0]);  acc1[1]=fmaf(w0.y,a,acc1[1]);
      acc1[2]=fmaf(w0.z,a,acc1[2]);  acc1[3]=fmaf(w0.w,a,acc1[3]);
      acc1[4]=fmaf(w1.x,a,acc1[4]);  acc1[5]=fmaf(w1.y,a,acc1[5]);
      acc1[6]=fmaf(w1.z,a,acc1[6]);  acc1[7]=fmaf(w1.w,a,acc1[7]);
      acc1[8]=fmaf(w2.x,a,acc1[8]);  acc1[9]=fmaf(w2.y,a,acc1[9]);
      acc1[10]=fmaf(w2.z,a,acc1[10]); acc1[11]=fmaf(w2.w,a,acc1[11]);
      acc1[12]=fmaf(w3.x,a,acc1[12]); acc1[13]=fmaf(w3.y,a,acc1[13]);
      acc1[14]=fmaf(w3.z,a,acc1[14]); acc1[15]=fmaf(w3.w,a,acc1[15]);
    }
    if (c) __syncthreads();   // prev chunk's hidS fully consumed
    #pragma unroll
    for (int j=0;j<16;j++)
      hidS[(wv*16+j)*64 + lane] = geluf_(acc1[j] + b1[h0+j]);
    __syncthreads();
    for (int k2=0;k2<64;k2++){
      float a = hidS[k2*64 + lane];
      int kg = c*64 + k2;
      const float4* wp = (const float4*)&W2t[(size_t)kg*96 + o0];
      float4 w0=wp[0], w1=wp[1], w2=wp[2], w3=wp[3], w4=wp[4], w5=wp[5];
      acc2[0]=fmaf(w0.x,a,acc2[0]);  acc2[1]=fmaf(w0.y,a,acc2[1]);
      acc2[2]=fmaf(w0.z,a,acc2[2]);  acc2[3]=fmaf(w0.w,a,acc2[3]);
      acc2[4]=fmaf(w1.x,a,acc2[4]);  acc2[5]=fmaf(w1.y,a,acc2[5]);
      acc2[6]=fmaf(w1.z,a,acc2[6]);  acc2[7]=fmaf(w1.w,a,acc2[7]);
      acc2[8]=fmaf(w2.x,a,acc2[8]);  acc2[9]=fmaf(w2.y,a,acc2[9]);
      acc2[10]=fmaf(w2.z,a,acc2[10]); acc2[11]=fmaf(w2.w,a,acc2[11]);
      acc2[12]=fmaf(w3.x,a,acc2[12]); acc2[13]=fmaf(w3.y,a,acc2[13]);
      acc2[14]=fmaf(w3.z,a,acc2[14]); acc2[15]=fmaf(w3.w,a,acc2[15]);
      acc2[16]=fmaf(w4.x,a,acc2[16]); acc2[17]=fmaf(w4.y,a,acc2[17]);
      acc2[18]=fmaf(w4.z,a,acc2[18]); acc2[19]=fmaf(w4.w,a,acc2[19]);
      acc2[20]=fmaf(w5.x,a,acc2[20]); acc2[21]=fmaf(w5.y,a,acc2[21]);
      acc2[22]=fmaf(w5.z,a,acc2[22]); acc2[23]=fmaf(w5.w,a,acc2[23]);
    }
  }
  #pragma unroll
  for (int j=0;j<24;j++){
    int o = o0 + j;
    size_t off = ((size_t)b*96+o)*NSPA + l0 + lane;
    dout[off] = acc2[j] + b2[o] + x[off];
  }
}

extern "C" void kernel_launch(void* const* d_in, const int* in_sizes, int n_in,
                              void* d_out, int out_size, void* d_ws, size_t ws_size,
                              hipStream_t stream) {
  const float* x        = (const float*)d_in[0];
  const float* c1w      = (const float*)d_in[1];
  const float* c1b      = (const float*)d_in[2];
  const float* c3w      = (const float*)d_in[3];
  const float* c3b      = (const float*)d_in[4];
  const float* gnw      = (const float*)d_in[5];
  const float* gnb      = (const float*)d_in[6];
  const float* in_proj  = (const float*)d_in[7];
  const float* conv1dw  = (const float*)d_in[8];
  const float* conv1db  = (const float*)d_in[9];
  const float* xprojw   = (const float*)d_in[10];
  const float* dtw      = (const float*)d_in[11];
  const float* dtb      = (const float*)d_in[12];
  const float* A_log    = (const float*)d_in[13];
  const float* ssm_D    = (const float*)d_in[14];
  const float* outprojw = (const float*)d_in[15];
  const float* W1       = (const float*)d_in[16];
  const float* b1       = (const float*)d_in[17];
  const float* W2       = (const float*)d_in[18];
  const float* b2       = (const float*)d_in[19];
  float* dout = (float*)d_out;

  float* ws = (float*)d_ws;
  const size_t o_st = 0;
  const size_t o_A  = 65536;
  const size_t o_B  = o_A + 12582912;
  const size_t o_C  = o_B + 12582912;
  const size_t o_D  = o_C + 12582912;
  const size_t o_E  = o_D + 6291456;
  const size_t o_F  = o_E + 6291456;
  float* st    = ws + o_st;
  float* P     = ws + o_A;            // 6,291,456 floats
  float* Hs    = ws + o_A + 6291456;  // 6,291,456 floats
  float* zg_t  = ws + o_B;
  float* xc_t  = ws + o_C;
  float* dbl_t = ws + o_D;
  float* x2b   = ws + o_E;
  float* hendb = ws + o_E;            // x2 dead after sppe_out
  float* outb  = ws + o_E;            // hend dead after scanB
  // o_F region: prepped weights + sigmoid gate
  float* W1t   = ws + o_F + 0;        // 36,864
  float* W2t   = ws + o_F + 40960;    // 36,864
  float* Wipt  = ws + o_F + 81920;    // 36,864
  float* xpWt  = ws + o_F + 122880;   // 9,216
  float* Wot   = ws + o_F + 139264;   // 18,432
  float* sigb  = ws + o_F + 200704;   // 524,288
  float* wtb   = st + ST_WT;          // 3,888

  hipMemsetAsync(st, 0, 65536*sizeof(float), stream);

  // --- all weight transposes ---
  k_prep<<<556, 256, 0, stream>>>(c3w, W1, W2, in_proj, xprojw, outprojw,
                                  wtb, W1t, W2t, Wipt, xpWt, Wot);
  // --- SPPE branch + inorm stats (gated array eliminated) ---
  k_stats<<<192, 1024, 0, stream>>>(x, st);
  k_gates<<<16, 128, 0, stream>>>(c1w, c1b, st);
  k_gated<<<192, 1024, 0, stream>>>(x, st);
  k_conv3<<<dim3(4,8,16), 256, 0, stream>>>(x, wtb, c3b, x2b, st);
  k_sppe_out<<<dim3(128,16), 256, 0, stream>>>(x, x2b, gnw, gnb, st, sigb);
  // --- fused in_proj (inorm) + conv1d + silu -> xc_t, zg_t (halo via LDS) ---
  k_front<<<dim3(512,2), 256, 0, stream>>>(x, Wipt, conv1dw, conv1db,
                                           st, xc_t, zg_t);
  // --- x_proj -> dbl_t token-major [B|C|dt] ---
  k_gemm_xp<<<dim3(512,2), 256, 0, stream>>>(xc_t, xpWt, dbl_t);
  // --- chunked selective scan (round-9 bodies; scanA Pp via sum-exp) ---
  k_scanA<<<dim3(NCH,2), 192, 0, stream>>>(xc_t, dbl_t, dtw, dtb, A_log, P, hendb);
  k_scanB<<<dim3(48,2), 1024, 0, stream>>>(P, hendb, Hs);
  // --- scanC with FUSED out_proj: writes outb directly ---
  k_scanC<<<dim3(NCH,2), 192, 0, stream>>>(xc_t, dbl_t, dtw, dtb, A_log, Hs,
                                           ssm_D, zg_t, Wot, outb);
  // --- stats of out + fully-fused MLP (round-5 proven 256-thr body) ---
  k_stats2<<<192, 256, 0, stream>>>(outb, st);
  k_mlpF<<<dim3(512,2), 256, 0, stream>>>(outb, sigb, st, W1t, b1, W2t, b2, x, dout);
}